// Round 1
// baseline (423.311 us; speedup 1.0000x reference)
//
#include <hip/hip_runtime.h>

#define H_DIM 128
#define L_SESS 50
#define B_SESS 10000
#define M_PAD 64
#define LDSTR 136   // LDS tile row stride in bf16 elems (128 + 8 pad -> conflict-free)
#define PSTR 68     // partial-e scratch row stride in floats (64 + 4 pad)

typedef __bf16 bf16x8 __attribute__((ext_vector_type(8)));
typedef float f32x4 __attribute__((ext_vector_type(4)));

static __device__ __forceinline__ unsigned short f2bf(float f) {
  unsigned int u = __float_as_uint(f);
  u += 0x7FFFu + ((u >> 16) & 1u);   // RNE
  return (unsigned short)(u >> 16);
}
static __device__ __forceinline__ float bf2f(unsigned short h) {
  return __uint_as_float(((unsigned int)h) << 16);
}

// -------- kernel 0: convert W2 (fp32 row-major [n][k]) -> bf16 into ws --------
__global__ __launch_bounds__(256) void cvt_w2_kernel(
    const float* __restrict__ w2, unsigned short* __restrict__ w2b) {
  int i = blockIdx.x * 256 + threadIdx.x;  // 4096 float4 chunks = 16384 elems
  float4 v = ((const float4*)w2)[i];
  ushort4 o;
  o.x = f2bf(v.x); o.y = f2bf(v.y); o.z = f2bf(v.z); o.w = f2bf(v.w);
  *(ushort4*)(w2b + (size_t)i * 4) = o;
}

// -------- kernel A: U[b][n] = sum_k W1[n][k]*x[last(b)][k] + b1[n] + b2[n] ----
// 625 blocks x 16 sessions; MFMA 16x16x32 bf16. U lives in d_out (overwritten
// later by the main kernel after it has consumed its row).
__global__ __launch_bounds__(256) void sess_u_kernel(
    const float* __restrict__ x, const float* __restrict__ w1,
    const float* __restrict__ w1b, const float* __restrict__ w2bias,
    float* __restrict__ U) {
  __shared__ __attribute__((aligned(16))) unsigned short W1s[H_DIM * LDSTR];
  __shared__ __attribute__((aligned(16))) unsigned short Vs[16 * LDSTR];
  const int t = threadIdx.x;
  const int s0 = blockIdx.x * 16;

  // stage W1 -> bf16 LDS, row-major [n][k], stride 136
  for (int i = t; i < 4096; i += 256) {
    float4 v = ((const float4*)w1)[i];
    int row = i >> 5;
    int col = (i & 31) * 4;
    ushort4 o;
    o.x = f2bf(v.x); o.y = f2bf(v.y); o.z = f2bf(v.z); o.w = f2bf(v.w);
    *(ushort4*)&W1s[row * LDSTR + col] = o;
  }
  // gather the 16 last-token rows -> bf16 LDS
  for (int i = t; i < 512; i += 256) {
    int j = i >> 5;
    int col = (i & 31) * 4;
    float4 v = ((const float4*)(x + ((size_t)(s0 + j) * L_SESS + (L_SESS - 1)) * H_DIM))[i & 31];
    ushort4 o;
    o.x = f2bf(v.x); o.y = f2bf(v.y); o.z = f2bf(v.z); o.w = f2bf(v.w);
    *(ushort4*)&Vs[j * LDSTR + col] = o;
  }
  __syncthreads();

  const int lane = t & 63, w = t >> 6, q = lane >> 4, c = lane & 15;
  const int n0 = (w * 2) * 16 + c;
  const int n1 = (w * 2 + 1) * 16 + c;
  f32x4 acc0 = {0.f, 0.f, 0.f, 0.f};
  f32x4 acc1 = {0.f, 0.f, 0.f, 0.f};
#pragma unroll
  for (int kt = 0; kt < 4; ++kt) {
    bf16x8 a  = *(const bf16x8*)&Vs[c * LDSTR + kt * 32 + q * 8];
    bf16x8 b0 = *(const bf16x8*)&W1s[n0 * LDSTR + kt * 32 + q * 8];
    bf16x8 b1 = *(const bf16x8*)&W1s[n1 * LDSTR + kt * 32 + q * 8];
    acc0 = __builtin_amdgcn_mfma_f32_16x16x32_bf16(a, b0, acc0, 0, 0, 0);
    acc1 = __builtin_amdgcn_mfma_f32_16x16x32_bf16(a, b1, acc1, 0, 0, 0);
  }
  float bias0 = w1b[n0] + w2bias[n0];
  float bias1 = w1b[n1] + w2bias[n1];
#pragma unroll
  for (int r = 0; r < 4; ++r) {
    int m = q * 4 + r;  // session within the 16-tile (C/D: row = quad*4+reg, col = lane&15)
    U[(size_t)(s0 + m) * H_DIM + n0] = acc0[r] + bias0;
    U[(size_t)(s0 + m) * H_DIM + n1] = acc1[r] + bias1;
  }
}

// -------- main kernel: one block per session, fully fused ---------------------
__global__ __launch_bounds__(256) void sess_attn_kernel(
    const float* __restrict__ x, const unsigned short* __restrict__ W2b,
    const float* __restrict__ U, const float* __restrict__ qw,
    const float* __restrict__ qb, float* __restrict__ out) {
  __shared__ __attribute__((aligned(16))) unsigned short Wb[H_DIM * LDSTR];  // 34816 B
  __shared__ __attribute__((aligned(16))) unsigned short Xb[M_PAD * LDSTR];  // 17408 B
  __shared__ float alpha_s[M_PAD];
  float* psc = (float*)Wb;  // [64][PSTR] partial-e scratch, aliases Wb after GEMM

  const int t = threadIdx.x;
  const int b = blockIdx.x;
  const int lane = t & 63, w = t >> 6, q = lane >> 4, c = lane & 15;
  const int n0 = (w * 2) * 16 + c;        // this wave's two 16-col tiles
  const int n1 = (w * 2 + 1) * 16 + c;

  // hoisted small loads (U row written by sess_u into d_out; L2-resident)
  const float un0 = U[(size_t)b * H_DIM + n0];
  const float un1 = U[(size_t)b * H_DIM + n1];
  const float qn0 = qw[n0];
  const float qn1 = qw[n1];
  const float qbv = qb[0];

  // stage W2 bf16 (L2-hot) -> LDS [n][k] stride 136
  for (int i = t; i < 2048; i += 256) {
    uint4 v = ((const uint4*)W2b)[i];
    int row = i >> 4;
    int col = (i & 15) * 8;
    *(uint4*)&Wb[row * LDSTR + col] = v;
  }
  // stage this session's 50 x-rows -> bf16 LDS (rows 50..63 left uninitialized;
  // their garbage stays confined to masked rows — MFMA rows are independent)
  const float* xs = x + (size_t)b * (L_SESS * H_DIM);
  for (int i = t; i < 1600; i += 256) {
    float4 v = ((const float4*)xs)[i];
    int row = i >> 5;
    int col = (i & 31) * 4;
    ushort4 o;
    o.x = f2bf(v.x); o.y = f2bf(v.y); o.z = f2bf(v.z); o.w = f2bf(v.w);
    *(ushort4*)&Xb[row * LDSTR + col] = o;
  }
  __syncthreads();

  // GEMM: D[64x32] per wave = Xs(64x128,bf16) @ W2^T tiles. col-split: A reused x2, B x4.
  f32x4 acc[4][2];
  const f32x4 zero4 = {0.f, 0.f, 0.f, 0.f};
#pragma unroll
  for (int mt = 0; mt < 4; ++mt) { acc[mt][0] = zero4; acc[mt][1] = zero4; }
#pragma unroll
  for (int kt = 0; kt < 4; ++kt) {
    bf16x8 a[4];
#pragma unroll
    for (int mt = 0; mt < 4; ++mt)
      a[mt] = *(const bf16x8*)&Xb[(mt * 16 + c) * LDSTR + kt * 32 + q * 8];
    bf16x8 b0 = *(const bf16x8*)&Wb[n0 * LDSTR + kt * 32 + q * 8];
    bf16x8 b1 = *(const bf16x8*)&Wb[n1 * LDSTR + kt * 32 + q * 8];
#pragma unroll
    for (int mt = 0; mt < 4; ++mt) {
      acc[mt][0] = __builtin_amdgcn_mfma_f32_16x16x32_bf16(a[mt], b0, acc[mt][0], 0, 0, 0);
      acc[mt][1] = __builtin_amdgcn_mfma_f32_16x16x32_bf16(a[mt], b1, acc[mt][1], 0, 0, 0);
    }
  }
  __syncthreads();  // all waves done reading Wb -> safe to alias psc over it

  // epilogue: h = sigmoid(acc + u), partial e = h*q summed over this wave's 2 cols
#pragma unroll
  for (int mt = 0; mt < 4; ++mt) {
#pragma unroll
    for (int r = 0; r < 4; ++r) {
      float t0 = acc[mt][0][r] + un0;
      float t1 = acc[mt][1][r] + un1;
      float h0 = 1.0f / (1.0f + __expf(-t0));
      float h1 = 1.0f / (1.0f + __expf(-t1));
      int row = mt * 16 + q * 4 + r;           // C/D: row = quad*4+reg
      psc[row * PSTR + w * 16 + c] = h0 * qn0 + h1 * qn1;
    }
  }
  __syncthreads();

  // wave 0: assemble e per row, masked stable softmax over the 50 real rows
  if (t < 64) {
    const float4* prow = (const float4*)(psc + t * PSTR);
    float s = 0.f;
#pragma unroll
    for (int j = 0; j < 16; ++j) {
      float4 v4 = prow[j];
      s += (v4.x + v4.y) + (v4.z + v4.w);
    }
    float e = s + qbv;
    float val = (t < L_SESS) ? e : -1.0e30f;
    float mx = val;
#pragma unroll
    for (int off = 32; off > 0; off >>= 1) mx = fmaxf(mx, __shfl_xor(mx, off));
    float z = (t < L_SESS) ? __expf(e - mx) : 0.f;
    float d = z;
#pragma unroll
    for (int off = 32; off > 0; off >>= 1) d += __shfl_xor(d, off);
    alpha_s[t] = z / d;
  }
  __syncthreads();

  // pooling: out[b][:] = sum_m alpha[m] * x[m][:]; 64 lanes x 2 cols each
  if (t < 64) {
    float s0 = 0.f, s1 = 0.f;
    for (int m = 0; m < L_SESS; ++m) {
      unsigned int pv = *(const unsigned int*)&Xb[m * LDSTR + 2 * t];
      float a = alpha_s[m];
      s0 += a * bf2f((unsigned short)(pv & 0xFFFFu));
      s1 += a * bf2f((unsigned short)(pv >> 16));
    }
    float2 o2;
    o2.x = s0;
    o2.y = s1;
    *(float2*)(out + (size_t)b * H_DIM + 2 * t) = o2;
  }
}

extern "C" void kernel_launch(void* const* d_in, const int* in_sizes, int n_in,
                              void* d_out, int out_size, void* d_ws, size_t ws_size,
                              hipStream_t stream) {
  const float* x    = (const float*)d_in[0];
  const float* w1   = (const float*)d_in[1];
  const float* w1b  = (const float*)d_in[2];
  const float* w2   = (const float*)d_in[3];
  const float* w2bi = (const float*)d_in[4];
  const float* qw   = (const float*)d_in[5];
  const float* qb   = (const float*)d_in[6];
  float* out = (float*)d_out;

  unsigned short* W2bf = (unsigned short*)d_ws;  // 32 KB of ws only
  float* U = out;                                 // U scratch lives in d_out

  cvt_w2_kernel<<<16, 256, 0, stream>>>(w2, W2bf);
  sess_u_kernel<<<B_SESS / 16, 256, 0, stream>>>(x, w1, w1b, w2bi, U);
  sess_attn_kernel<<<B_SESS, 256, 0, stream>>>(x, W2bf, U, qw, qb, out);
}

// Round 2
// 417.532 us; speedup vs baseline: 1.0138x; 1.0138x over previous
//
#include <hip/hip_runtime.h>

#define H_DIM 128
#define L_SESS 50
#define B_SESS 10000
#define LDSTR 136   // Xb row stride in bf16 elems (128+8 pad)
#define ESTR 5      // epart row stride in floats (4 waves + 1 pad -> conflict-free)

typedef __bf16 bf16_t;
typedef __bf16 bf16x8 __attribute__((ext_vector_type(8)));
typedef float f32x4 __attribute__((ext_vector_type(4)));

// -------- kernel 0: convert W1+W2 fp32 -> bf16 in ws; combined bias ----------
__global__ __launch_bounds__(256) void cvt_kernel(
    const float* __restrict__ w1, const float* __restrict__ w2,
    const float* __restrict__ w1b, const float* __restrict__ w2bi,
    unsigned short* __restrict__ wout, float* __restrict__ bias12) {
  int i = blockIdx.x * 256 + threadIdx.x;  // 8192 float4 chunks: W1 then W2
  float4 v = (i < 4096) ? ((const float4*)w1)[i] : ((const float4*)w2)[i - 4096];
  union { bf16_t h[4]; ushort4 u4; } tmp;
  tmp.h[0] = (bf16_t)v.x; tmp.h[1] = (bf16_t)v.y;
  tmp.h[2] = (bf16_t)v.z; tmp.h[3] = (bf16_t)v.w;
  *(ushort4*)(wout + (size_t)4 * i) = tmp.u4;
  if (i < H_DIM) bias12[i] = w1b[i] + w2bi[i];  // only block 0 hits this
}

// -------- main kernel: one block per session, fully fused (incl. u matvec) ---
__global__ __launch_bounds__(256, 4) void sess_attn_kernel(
    const float* __restrict__ x, const unsigned short* __restrict__ Wb,
    const float* __restrict__ bias12, const float* __restrict__ qw,
    const float* __restrict__ qb, float* __restrict__ out) {
  __shared__ __attribute__((aligned(16))) unsigned short Xb[64 * LDSTR];  // 17408 B
  __shared__ float epart[64 * ESTR];   // per-(row,wave) e partials, 1280 B
  __shared__ float alpha_s[64];
  __shared__ float pool_s[H_DIM];

  const int t = threadIdx.x;
  const int b = blockIdx.x;
  const int lane = t & 63, w = t >> 6, q = lane >> 4, c = lane & 15;
  const int n0 = w * 32 + c;        // this wave's two 16-col tiles
  const int n1 = w * 32 + 16 + c;

  const float* xs = x + (size_t)b * (L_SESS * H_DIM);
  const bf16x8* W1v = (const bf16x8*)(Wb);            // [n][k] bf16
  const bf16x8* W2v = (const bf16x8*)(Wb + 16384);

  // W2 B-fragments straight into registers (ws is L2-hot across all blocks)
  bf16x8 bw2[4][2];
#pragma unroll
  for (int kt = 0; kt < 4; ++kt) {
    bw2[kt][0] = W2v[(n0 * H_DIM + kt * 32 + q * 8) >> 3];
    bw2[kt][1] = W2v[(n1 * H_DIM + kt * 32 + q * 8) >> 3];
  }
  const float bias0 = bias12[n0], bias1 = bias12[n1];
  const float qn0 = qw[n0], qn1 = qw[n1], qbv = qb[0];

  // stage this session's 50 x-rows -> bf16 LDS (rows 50..63 garbage; rows are
  // independent through MFMA and masked in the softmax)
  for (int i = t; i < 1600; i += 256) {
    float4 v = ((const float4*)xs)[i];
    int row = i >> 5, col = (i & 31) * 4;
    union { bf16_t h[4]; ushort4 u4; } tmp;
    tmp.h[0] = (bf16_t)v.x; tmp.h[1] = (bf16_t)v.y;
    tmp.h[2] = (bf16_t)v.z; tmp.h[3] = (bf16_t)v.w;
    *(ushort4*)&Xb[row * LDSTR + col] = tmp.u4;
  }
  __syncthreads();

  const f32x4 zero4 = {0.f, 0.f, 0.f, 0.f};

  // u = W1 . x[last] via broadcast-A MFMA (all A rows = row 49) — replaces the
  // old sess_u kernel. W1 frags loaded here (L2) so they don't sit in regs.
  f32x4 accu[2] = {zero4, zero4};
#pragma unroll
  for (int kt = 0; kt < 4; ++kt) {
    bf16x8 av = *(const bf16x8*)&Xb[49 * LDSTR + kt * 32 + q * 8];  // broadcast
    accu[0] = __builtin_amdgcn_mfma_f32_16x16x32_bf16(
        av, W1v[(n0 * H_DIM + kt * 32 + q * 8) >> 3], accu[0], 0, 0, 0);
    accu[1] = __builtin_amdgcn_mfma_f32_16x16x32_bf16(
        av, W1v[(n1 * H_DIM + kt * 32 + q * 8) >> 3], accu[1], 0, 0, 0);
  }
  const float u0 = accu[0][0] + bias0;  // all acc rows identical -> reg 0
  const float u1 = accu[1][0] + bias1;

  // GEMM: D[64x32] per wave = Xb(64x128) @ W2^T col-tiles (B in registers)
  f32x4 acc[4][2];
#pragma unroll
  for (int mt = 0; mt < 4; ++mt) { acc[mt][0] = zero4; acc[mt][1] = zero4; }
#pragma unroll
  for (int kt = 0; kt < 4; ++kt) {
#pragma unroll
    for (int mt = 0; mt < 4; ++mt) {
      bf16x8 a = *(const bf16x8*)&Xb[(mt * 16 + c) * LDSTR + kt * 32 + q * 8];
      acc[mt][0] = __builtin_amdgcn_mfma_f32_16x16x32_bf16(a, bw2[kt][0], acc[mt][0], 0, 0, 0);
      acc[mt][1] = __builtin_amdgcn_mfma_f32_16x16x32_bf16(a, bw2[kt][1], acc[mt][1], 0, 0, 0);
    }
  }

  // epilogue: h = sigmoid(acc+u); p = h.q partial; reduce over the wave's 32
  // cols with shfl-xor (within 16-lane groups), one float per (row, wave)
#pragma unroll
  for (int mt = 0; mt < 4; ++mt) {
#pragma unroll
    for (int r = 0; r < 4; ++r) {
      float t0 = acc[mt][0][r] + u0;
      float t1 = acc[mt][1][r] + u1;
      float h0 = 1.0f / (1.0f + __expf(-t0));
      float h1 = 1.0f / (1.0f + __expf(-t1));
      float p = h0 * qn0 + h1 * qn1;
#pragma unroll
      for (int off = 1; off <= 8; off <<= 1) p += __shfl_xor(p, off);
      if (c == 0) epart[(mt * 16 + q * 4 + r) * ESTR + w] = p;  // C/D row = q*4+r
    }
  }
  __syncthreads();

  // wave 0: e per row, masked stable softmax over the 50 real rows
  if (t < 64) {
    float e = qbv;
#pragma unroll
    for (int j = 0; j < 4; ++j) e += epart[t * ESTR + j];
    float val = (t < L_SESS) ? e : -1.0e30f;
    float mx = val;
#pragma unroll
    for (int off = 32; off > 0; off >>= 1) mx = fmaxf(mx, __shfl_xor(mx, off));
    float z = (t < L_SESS) ? __expf(e - mx) : 0.f;
    float d = z;
#pragma unroll
    for (int off = 32; off > 0; off >>= 1) d += __shfl_xor(d, off);
    alpha_s[t] = z / d;
  }
  __syncthreads();

  // pooling from global fp32 x (L2-hot): 256 threads = 128 cols x 2 row-halves
  const int col = t & 127, half = t >> 7;
  const float* xp = xs + (size_t)(half * 25) * H_DIM + col;
  float s = 0.f;
#pragma unroll
  for (int m = 0; m < 25; ++m) s += alpha_s[half * 25 + m] * xp[(size_t)m * H_DIM];
  if (half) pool_s[col] = s;
  __syncthreads();
  if (!half) out[(size_t)b * H_DIM + col] = s + pool_s[col];
}

extern "C" void kernel_launch(void* const* d_in, const int* in_sizes, int n_in,
                              void* d_out, int out_size, void* d_ws, size_t ws_size,
                              hipStream_t stream) {
  const float* x    = (const float*)d_in[0];
  const float* w1   = (const float*)d_in[1];
  const float* w1b  = (const float*)d_in[2];
  const float* w2   = (const float*)d_in[3];
  const float* w2bi = (const float*)d_in[4];
  const float* qw   = (const float*)d_in[5];
  const float* qb   = (const float*)d_in[6];
  float* out = (float*)d_out;

  unsigned short* Wb = (unsigned short*)d_ws;          // 64 KB bf16 W1|W2
  float* bias12 = (float*)((char*)d_ws + 65536);       // 512 B combined bias

  cvt_kernel<<<32, 256, 0, stream>>>(w1, w2, w1b, w2bi, Wb, bias12);
  sess_attn_kernel<<<B_SESS, 256, 0, stream>>>(x, Wb, bias12, qw, qb, out);
}

// Round 3
// 401.366 us; speedup vs baseline: 1.0547x; 1.0403x over previous
//
#include <hip/hip_runtime.h>

#define H_DIM 128
#define L_SESS 50
#define B_SESS 10000
#define LDSTR 136   // Xb row stride in bf16 elems (128+8 pad)
#define ESTR 5      // epart row stride in floats (4 waves + 1 pad)

typedef __bf16 bf16_t;
typedef __bf16 bf16x8 __attribute__((ext_vector_type(8)));
typedef float f32x4 __attribute__((ext_vector_type(4)));

// -------- kernel 0: convert W1+W2 fp32 -> bf16 in ws; combined bias ----------
__global__ __launch_bounds__(256) void cvt_kernel(
    const float* __restrict__ w1, const float* __restrict__ w2,
    const float* __restrict__ w1b, const float* __restrict__ w2bi,
    unsigned short* __restrict__ wout, float* __restrict__ bias12) {
  int i = blockIdx.x * 256 + threadIdx.x;  // 8192 float4 chunks: W1 then W2
  float4 v = (i < 4096) ? ((const float4*)w1)[i] : ((const float4*)w2)[i - 4096];
  union { bf16_t h[4]; ushort4 u4; } tmp;
  tmp.h[0] = (bf16_t)v.x; tmp.h[1] = (bf16_t)v.y;
  tmp.h[2] = (bf16_t)v.z; tmp.h[3] = (bf16_t)v.w;
  *(ushort4*)(wout + (size_t)4 * i) = tmp.u4;
  if (i < H_DIM) bias12[i] = w1b[i] + w2bi[i];  // only block 0
}

// -------- main kernel: one block per session, fully fused --------------------
// launch_bounds(256,8): 8 blocks/CU (32 waves). Reg budget 64/wave -> W1/W2
// B-fragments are loaded from the L2-hot ws copy inside the loops, NOT cached.
__global__ __launch_bounds__(256, 8) void sess_attn_kernel(
    const float* __restrict__ x, const unsigned short* __restrict__ Wb,
    const float* __restrict__ bias12, const float* __restrict__ qw,
    const float* __restrict__ qb, float* __restrict__ out) {
  __shared__ __attribute__((aligned(16))) unsigned short Xb[64 * LDSTR];  // 17408 B
  __shared__ float epart[64 * ESTR];   // 1280 B
  __shared__ float alpha_s[64];

  const int t = threadIdx.x;
  const int b = blockIdx.x;
  const int lane = t & 63, w = t >> 6, q = lane >> 4, c = lane & 15;
  const int n0 = w * 32 + c;
  const int n1 = n0 + 16;

  const float* xs = x + (size_t)b * (L_SESS * H_DIM);
  const float4* xsv = (const float4*)xs;
  const bf16x8* W1v = (const bf16x8*)(Wb);            // [n][k] bf16
  const bf16x8* W2v = (const bf16x8*)(Wb + 16384);

  // ---- stage x (50 rows fp32 -> bf16 LDS): issue ALL loads first (MLP) ----
  float4 v[6];
#pragma unroll
  for (int j = 0; j < 6; ++j) v[j] = xsv[t + 256 * j];
  float4 v6;
  if (t < 64) v6 = xsv[1536 + t];

  const float bias0 = bias12[n0], bias1 = bias12[n1];
  const float qn0 = qw[n0], qn1 = qw[n1], qbv = qb[0];

#pragma unroll
  for (int j = 0; j < 6; ++j) {
    int i = t + 256 * j;
    int row = i >> 5, col = (i & 31) * 4;
    union { bf16_t h[4]; ushort4 u4; } tmp;
    tmp.h[0] = (bf16_t)v[j].x; tmp.h[1] = (bf16_t)v[j].y;
    tmp.h[2] = (bf16_t)v[j].z; tmp.h[3] = (bf16_t)v[j].w;
    *(ushort4*)&Xb[row * LDSTR + col] = tmp.u4;
  }
  if (t < 64) {
    int i = 1536 + t;
    int row = i >> 5, col = (i & 31) * 4;
    union { bf16_t h[4]; ushort4 u4; } tmp;
    tmp.h[0] = (bf16_t)v6.x; tmp.h[1] = (bf16_t)v6.y;
    tmp.h[2] = (bf16_t)v6.z; tmp.h[3] = (bf16_t)v6.w;
    *(ushort4*)&Xb[row * LDSTR + col] = tmp.u4;
  }
  __syncthreads();

  const f32x4 zero4 = {0.f, 0.f, 0.f, 0.f};

  // ---- u = W1 . x[last] via broadcast-A MFMA (W1 frags from L2, in-loop) ----
  f32x4 accu0 = zero4, accu1 = zero4;
#pragma unroll
  for (int kt = 0; kt < 4; ++kt) {
    const int ko = kt * 32 + q * 8;
    bf16x8 av = *(const bf16x8*)&Xb[49 * LDSTR + ko];  // broadcast row 49
    accu0 = __builtin_amdgcn_mfma_f32_16x16x32_bf16(
        av, W1v[(n0 * H_DIM + ko) >> 3], accu0, 0, 0, 0);
    accu1 = __builtin_amdgcn_mfma_f32_16x16x32_bf16(
        av, W1v[(n1 * H_DIM + ko) >> 3], accu1, 0, 0, 0);
  }
  const float u0 = accu0[0] + bias0;  // all acc rows identical
  const float u1 = accu1[0] + bias1;

  // ---- GEMM: D[64x32]/wave = Xb(64x128) @ W2^T cols; B frags in-loop (L2) ----
  f32x4 acc[4][2];
#pragma unroll
  for (int mt = 0; mt < 4; ++mt) { acc[mt][0] = zero4; acc[mt][1] = zero4; }
#pragma unroll
  for (int kt = 0; kt < 4; ++kt) {
    const int ko = kt * 32 + q * 8;
    bf16x8 b0 = W2v[(n0 * H_DIM + ko) >> 3];
    bf16x8 b1 = W2v[(n1 * H_DIM + ko) >> 3];
#pragma unroll
    for (int mt = 0; mt < 4; ++mt) {
      bf16x8 a = *(const bf16x8*)&Xb[(mt * 16 + c) * LDSTR + ko];
      acc[mt][0] = __builtin_amdgcn_mfma_f32_16x16x32_bf16(a, b0, acc[mt][0], 0, 0, 0);
      acc[mt][1] = __builtin_amdgcn_mfma_f32_16x16x32_bf16(a, b1, acc[mt][1], 0, 0, 0);
    }
  }

  // ---- epilogue: h=sigmoid(acc+u); e-partials reduced over 32 cols/wave ----
#pragma unroll
  for (int mt = 0; mt < 4; ++mt) {
#pragma unroll
    for (int r = 0; r < 4; ++r) {
      float t0 = acc[mt][0][r] + u0;
      float t1 = acc[mt][1][r] + u1;
      float h0 = 1.0f / (1.0f + __expf(-t0));
      float h1 = 1.0f / (1.0f + __expf(-t1));
      float p = h0 * qn0 + h1 * qn1;
#pragma unroll
      for (int off = 1; off <= 8; off <<= 1) p += __shfl_xor(p, off);
      if (c == 0) epart[(mt * 16 + q * 4 + r) * ESTR + w] = p;  // C/D row=q*4+r
    }
  }
  __syncthreads();

  // ---- wave 0: masked stable softmax over the 50 real rows ----
  if (t < 64) {
    float e = qbv;
#pragma unroll
    for (int j = 0; j < 4; ++j) e += epart[t * ESTR + j];
    float val = (t < L_SESS) ? e : -1.0e30f;
    float mx = val;
#pragma unroll
    for (int off = 32; off > 0; off >>= 1) mx = fmaxf(mx, __shfl_xor(mx, off));
    float z = (t < L_SESS) ? __expf(e - mx) : 0.f;
    float d = z;
#pragma unroll
    for (int off = 32; off > 0; off >>= 1) d += __shfl_xor(d, off);
    alpha_s[t] = z / d;
  }
  __syncthreads();

  // ---- pooling from LDS bf16: 128 threads, one full column each ----
  if (t < H_DIM) {
    float s = 0.f;
#pragma unroll
    for (int m = 0; m < L_SESS; ++m) {
      unsigned short pv = Xb[m * LDSTR + t];
      s += alpha_s[m] * __uint_as_float(((unsigned int)pv) << 16);
    }
    out[(size_t)b * H_DIM + t] = s;
  }
}

extern "C" void kernel_launch(void* const* d_in, const int* in_sizes, int n_in,
                              void* d_out, int out_size, void* d_ws, size_t ws_size,
                              hipStream_t stream) {
  const float* x    = (const float*)d_in[0];
  const float* w1   = (const float*)d_in[1];
  const float* w1b  = (const float*)d_in[2];
  const float* w2   = (const float*)d_in[3];
  const float* w2bi = (const float*)d_in[4];
  const float* qw   = (const float*)d_in[5];
  const float* qb   = (const float*)d_in[6];
  float* out = (float*)d_out;

  unsigned short* Wb = (unsigned short*)d_ws;          // 64 KB bf16 W1|W2
  float* bias12 = (float*)((char*)d_ws + 65536);       // 512 B combined bias

  cvt_kernel<<<32, 256, 0, stream>>>(w1, w2, w1b, w2bi, Wb, bias12);
  sess_attn_kernel<<<B_SESS, 256, 0, stream>>>(x, Wb, bias12, qw, qb, out);
}

// Round 4
// 393.681 us; speedup vs baseline: 1.0753x; 1.0195x over previous
//
#include <hip/hip_runtime.h>

#define H_DIM 128
#define L_SESS 50
#define B_SESS 10000
#define NBLK 1024   // persistent blocks: 4/CU x 256 CU
#define NITER 10    // ceil(B_SESS / NBLK)
#define LDSTR 136   // Xb row stride in bf16 elems (128+8 pad)
#define ESTR 5      // epart row stride in floats

typedef __bf16 bf16_t;
typedef __bf16 bf16x8 __attribute__((ext_vector_type(8)));
typedef float f32x4 __attribute__((ext_vector_type(4)));

// -------- kernel 0: W2 fp32 -> bf16 in ws; combined bias ---------------------
__global__ __launch_bounds__(256) void cvt_kernel(
    const float* __restrict__ w2, const float* __restrict__ w1b,
    const float* __restrict__ w2bi, unsigned short* __restrict__ w2out,
    float* __restrict__ bias12) {
  int i = blockIdx.x * 256 + threadIdx.x;  // 4096 float4 chunks
  float4 v = ((const float4*)w2)[i];
  union { bf16_t h[4]; ushort4 u4; } tmp;
  tmp.h[0] = (bf16_t)v.x; tmp.h[1] = (bf16_t)v.y;
  tmp.h[2] = (bf16_t)v.z; tmp.h[3] = (bf16_t)v.w;
  *(ushort4*)(w2out + (size_t)4 * i) = tmp.u4;
  if (i < H_DIM) bias12[i] = w1b[i] + w2bi[i];  // block 0 only
}

// -------- kernel A: U[b][n] = W1[n].x[last(b)] + b1[n] + b2[n]  (r1-verified)
__global__ __launch_bounds__(256) void sess_u_kernel(
    const float* __restrict__ x, const float* __restrict__ w1,
    const float* __restrict__ bias12, float* __restrict__ U) {
  __shared__ __attribute__((aligned(16))) unsigned short W1s[H_DIM * LDSTR];
  __shared__ __attribute__((aligned(16))) unsigned short Vs[16 * LDSTR];
  const int t = threadIdx.x;
  const int s0 = blockIdx.x * 16;
  for (int i = t; i < 4096; i += 256) {
    float4 v = ((const float4*)w1)[i];
    int row = i >> 5, col = (i & 31) * 4;
    union { bf16_t h[4]; ushort4 u4; } tmp;
    tmp.h[0] = (bf16_t)v.x; tmp.h[1] = (bf16_t)v.y;
    tmp.h[2] = (bf16_t)v.z; tmp.h[3] = (bf16_t)v.w;
    *(ushort4*)&W1s[row * LDSTR + col] = tmp.u4;
  }
  for (int i = t; i < 512; i += 256) {
    int j = i >> 5, col = (i & 31) * 4;
    float4 v = ((const float4*)(x + ((size_t)(s0 + j) * L_SESS + (L_SESS - 1)) * H_DIM))[i & 31];
    union { bf16_t h[4]; ushort4 u4; } tmp;
    tmp.h[0] = (bf16_t)v.x; tmp.h[1] = (bf16_t)v.y;
    tmp.h[2] = (bf16_t)v.z; tmp.h[3] = (bf16_t)v.w;
    *(ushort4*)&Vs[j * LDSTR + col] = tmp.u4;
  }
  __syncthreads();
  const int lane = t & 63, w = t >> 6, q = lane >> 4, c = lane & 15;
  const int n0 = (w * 2) * 16 + c, n1 = (w * 2 + 1) * 16 + c;
  const f32x4 zero4 = {0.f, 0.f, 0.f, 0.f};
  f32x4 acc0 = zero4, acc1 = zero4;
#pragma unroll
  for (int kt = 0; kt < 4; ++kt) {
    bf16x8 a  = *(const bf16x8*)&Vs[c * LDSTR + kt * 32 + q * 8];
    bf16x8 b0 = *(const bf16x8*)&W1s[n0 * LDSTR + kt * 32 + q * 8];
    bf16x8 b1 = *(const bf16x8*)&W1s[n1 * LDSTR + kt * 32 + q * 8];
    acc0 = __builtin_amdgcn_mfma_f32_16x16x32_bf16(a, b0, acc0, 0, 0, 0);
    acc1 = __builtin_amdgcn_mfma_f32_16x16x32_bf16(a, b1, acc1, 0, 0, 0);
  }
  float bias0 = bias12[n0], bias1 = bias12[n1];
#pragma unroll
  for (int r = 0; r < 4; ++r) {
    int m = q * 4 + r;  // C/D: row = quad*4+reg
    U[(size_t)(s0 + m) * H_DIM + n0] = acc0[r] + bias0;
    U[(size_t)(s0 + m) * H_DIM + n1] = acc1[r] + bias1;
  }
}

// -------- main: persistent blocks, register-prefetch pipeline ----------------
__global__ __launch_bounds__(256, 4) void sess_attn_kernel(
    const float* __restrict__ x, const unsigned short* __restrict__ W2b,
    const float* __restrict__ U, const float* __restrict__ qw,
    const float* __restrict__ qb, float* __restrict__ out) {
  __shared__ __attribute__((aligned(16))) unsigned short Xb[64 * LDSTR];
  __shared__ float epart[64 * ESTR];
  __shared__ float alpha_s[64];

  const int t = threadIdx.x;
  const int lane = t & 63, w = t >> 6, q = lane >> 4, c = lane & 15;
  const int n0 = w * 32 + c, n1 = n0 + 16;

  // loop-invariant: W2 B-fragments in registers (one L2 read per block)
  const bf16x8* W2v = (const bf16x8*)W2b;
  bf16x8 bw2[4][2];
#pragma unroll
  for (int kt = 0; kt < 4; ++kt) {
    bw2[kt][0] = W2v[(n0 * H_DIM + kt * 32 + q * 8) >> 3];
    bw2[kt][1] = W2v[(n1 * H_DIM + kt * 32 + q * 8) >> 3];
  }
  const float qn0 = qw[n0], qn1 = qw[n1], qbv = qb[0];

  int s = blockIdx.x;
  // prologue: issue session-s loads into registers
  int sc = (s < B_SESS) ? s : (B_SESS - 1);
  const float4* xv = (const float4*)(x + (size_t)sc * (L_SESS * H_DIM));
  float4 v[6];
#pragma unroll
  for (int j = 0; j < 6; ++j) v[j] = xv[t + 256 * j];
  float4 v6;
  if (t < 64) v6 = xv[1536 + t];
  float unx0 = U[(size_t)sc * H_DIM + n0];
  float unx1 = U[(size_t)sc * H_DIM + n1];

  const f32x4 zero4 = {0.f, 0.f, 0.f, 0.f};

  for (int it = 0; it < NITER; ++it) {
    __syncthreads();  // prev pooling done reading Xb
    const float u0 = unx0, u1 = unx1;

    // convert registers -> bf16 LDS
#pragma unroll
    for (int j = 0; j < 6; ++j) {
      int i = t + 256 * j;
      int row = i >> 5, col = (i & 31) * 4;
      union { bf16_t h[4]; ushort4 u4; } tmp;
      tmp.h[0] = (bf16_t)v[j].x; tmp.h[1] = (bf16_t)v[j].y;
      tmp.h[2] = (bf16_t)v[j].z; tmp.h[3] = (bf16_t)v[j].w;
      *(ushort4*)&Xb[row * LDSTR + col] = tmp.u4;
    }
    if (t < 64) {
      int i = 1536 + t;
      int row = i >> 5, col = (i & 31) * 4;
      union { bf16_t h[4]; ushort4 u4; } tmp;
      tmp.h[0] = (bf16_t)v6.x; tmp.h[1] = (bf16_t)v6.y;
      tmp.h[2] = (bf16_t)v6.z; tmp.h[3] = (bf16_t)v6.w;
      *(ushort4*)&Xb[row * LDSTR + col] = tmp.u4;
    }
    __syncthreads();

    // issue NEXT session's loads (in flight across GEMM/epilogue/pool)
    if (it + 1 < NITER) {
      int sn = s + NBLK;
      int snc = (sn < B_SESS) ? sn : (B_SESS - 1);
      const float4* xn = (const float4*)(x + (size_t)snc * (L_SESS * H_DIM));
#pragma unroll
      for (int j = 0; j < 6; ++j) v[j] = xn[t + 256 * j];
      if (t < 64) v6 = xn[1536 + t];
      unx0 = U[(size_t)snc * H_DIM + n0];
      unx1 = U[(size_t)snc * H_DIM + n1];
    }

    // GEMM: D[64x32]/wave = Xb(64x128) @ W2^T cols (B in registers)
    f32x4 acc[4][2];
#pragma unroll
    for (int mt = 0; mt < 4; ++mt) { acc[mt][0] = zero4; acc[mt][1] = zero4; }
#pragma unroll
    for (int kt = 0; kt < 4; ++kt) {
      const int ko = kt * 32 + q * 8;
#pragma unroll
      for (int mt = 0; mt < 4; ++mt) {
        bf16x8 a = *(const bf16x8*)&Xb[(mt * 16 + c) * LDSTR + ko];
        acc[mt][0] = __builtin_amdgcn_mfma_f32_16x16x32_bf16(a, bw2[kt][0], acc[mt][0], 0, 0, 0);
        acc[mt][1] = __builtin_amdgcn_mfma_f32_16x16x32_bf16(a, bw2[kt][1], acc[mt][1], 0, 0, 0);
      }
    }

    // epilogue: h=sigmoid(acc+u); per-(row,wave) e-partials via shfl over cols
#pragma unroll
    for (int mt = 0; mt < 4; ++mt) {
#pragma unroll
      for (int r = 0; r < 4; ++r) {
        float t0 = acc[mt][0][r] + u0;
        float t1 = acc[mt][1][r] + u1;
        float h0 = 1.0f / (1.0f + __expf(-t0));
        float h1 = 1.0f / (1.0f + __expf(-t1));
        float p = h0 * qn0 + h1 * qn1;
#pragma unroll
        for (int off = 1; off <= 8; off <<= 1) p += __shfl_xor(p, off);
        if (c == 0) epart[(mt * 16 + q * 4 + r) * ESTR + w] = p;  // row=q*4+r
      }
    }
    __syncthreads();

    // wave 0: masked stable softmax over the 50 real rows
    if (t < 64) {
      float e = qbv;
#pragma unroll
      for (int j = 0; j < 4; ++j) e += epart[t * ESTR + j];
      float val = (t < L_SESS) ? e : -1.0e30f;
      float mx = val;
#pragma unroll
      for (int off = 32; off > 0; off >>= 1) mx = fmaxf(mx, __shfl_xor(mx, off));
      float z = (t < L_SESS) ? __expf(e - mx) : 0.f;
      float d = z;
#pragma unroll
      for (int off = 32; off > 0; off >>= 1) d += __shfl_xor(d, off);
      alpha_s[t] = z / d;
    }
    __syncthreads();

    // pooling from LDS bf16: 128 threads, one column each
    if (t < H_DIM) {
      float acc_p = 0.f;
#pragma unroll
      for (int m = 0; m < L_SESS; ++m) {
        unsigned short pv = Xb[m * LDSTR + t];
        acc_p += alpha_s[m] * __uint_as_float(((unsigned int)pv) << 16);
      }
      if (s < B_SESS) out[(size_t)s * H_DIM + t] = acc_p;
    }
    s += NBLK;
  }
}

extern "C" void kernel_launch(void* const* d_in, const int* in_sizes, int n_in,
                              void* d_out, int out_size, void* d_ws, size_t ws_size,
                              hipStream_t stream) {
  const float* x    = (const float*)d_in[0];
  const float* w1   = (const float*)d_in[1];
  const float* w1b  = (const float*)d_in[2];
  const float* w2   = (const float*)d_in[3];
  const float* w2bi = (const float*)d_in[4];
  const float* qw   = (const float*)d_in[5];
  const float* qb   = (const float*)d_in[6];
  float* out = (float*)d_out;

  unsigned short* W2bf = (unsigned short*)d_ws;            // 32 KB
  float* bias12 = (float*)((char*)d_ws + 32768);           // 512 B
  float* U = (float*)((char*)d_ws + 36864);                // 5.12 MB

  cvt_kernel<<<16, 256, 0, stream>>>(w2, w1b, w2bi, W2bf, bias12);
  sess_u_kernel<<<B_SESS / 16, 256, 0, stream>>>(x, w1, bias12, U);
  sess_attn_kernel<<<NBLK, 256, 0, stream>>>(x, W2bf, U, qw, qb, out);
}